// Round 2
// baseline (5390.143 us; speedup 1.0000x reference)
//
#include <hip/hip_runtime.h>
#include <math.h>

#define NP 2048           // points per batch (n == m)
#define DF 256            // feature dim
#define NPROB 8           // 2 OTs * 4 batches
#define NTOT 8192         // total rows per feature tensor

constexpr float F_MU  = 1.0f / 2048.0f;   // uniform marginal 1/n
constexpr float SQ    = 65535.0f;         // K u16 quantization scale
constexpr float EPS_U = 65535.0f * 1e-8f; // stab for u-update (scale-consistent)
constexpr float EPS_V = 1e-8f;            // stab for v-update (unscaled)

// workspace layout (float units)
constexpr size_t OFF_K   = 0;                            // ushort[8*2048*2048]
constexpr size_t SZ_Kf   = (size_t)NPROB * NP * NP / 2;  // 16,777,216 floats
constexpr size_t OFF_VA  = OFF_K + SZ_Kf;                // 3 ping-pong-pong buffers
constexpr size_t SZ_VA   = (size_t)3 * NPROB * NP;
constexpr size_t OFF_U   = OFF_VA + SZ_VA;
constexpr size_t SZ_U    = (size_t)NPROB * NP;
constexpr size_t OFF_INV = OFF_U + SZ_U;
constexpr size_t SZ_INV  = (size_t)3 * NTOT;
constexpr size_t OFF_SUM = OFF_INV + SZ_INV;

__device__ inline float4 unpack4(unsigned a, unsigned b) {
    return make_float4((float)(a & 0xffffu), (float)(a >> 16),
                       (float)(b & 0xffffu), (float)(b >> 16));
}

// ---------------------------------------------------------------- row norms
__global__ __launch_bounds__(256) void k_norms(const float* __restrict__ src,
                                               const float* __restrict__ tgt,
                                               const float* __restrict__ gen,
                                               float* __restrict__ inv) {
    int gw   = (blockIdx.x * 256 + threadIdx.x) >> 6;   // 0 .. 3*8192-1
    int lane = threadIdx.x & 63;
    int a = gw >> 13;
    int r = gw & 8191;
    const float* base = (a == 0 ? src : (a == 1 ? tgt : gen)) + (size_t)r * DF;
    float4 x = reinterpret_cast<const float4*>(base)[lane];
    float s = x.x * x.x + x.y * x.y + x.z * x.z + x.w * x.w;
    #pragma unroll
    for (int off = 32; off; off >>= 1) s += __shfl_xor(s, off);
    if (lane == 0) inv[gw] = 1.0f / (sqrtf(s) + 1e-8f);
}

// ---------------------------------------------------------------- zero init
__global__ void k_init(float* __restrict__ va0, float* __restrict__ sum) {
    int i = blockIdx.x * 256 + threadIdx.x;
    if (i < NPROB * NP) va0[i] = 0.0f;
    if (i == 0) sum[0] = 0.0f;
}

// ---------------------------------------------------------------- K = round(65535*exp(cos-1))
// 128x128 tile, 8x8 micro-tile. LDS rows padded to 20 floats (80B, 16B-aligned)
// so fragments load as ds_read_b128: 16 b128 reads per 256 FMAs.
#define TK 16
#define TP 20
__global__ __launch_bounds__(256) void k_build(const float* __restrict__ src,
                                               const float* __restrict__ tgt,
                                               const float* __restrict__ gen,
                                               const float* __restrict__ inv,
                                               unsigned short* __restrict__ K) {
    __shared__ float As[128][TP];
    __shared__ float Bs[128][TP];
    int bid = blockIdx.x;          // 2048 = 8 problems * 16 * 16 tiles
    int p   = bid >> 8;
    int t   = bid & 255;
    int ti  = t >> 4, tj = t & 15;
    int ot  = p >> 2, b = p & 3;
    const float* X    = (ot == 0) ? src : tgt;
    const float* Y    = (ot == 0) ? tgt : gen;
    const float* invx = inv + (ot == 0 ? 0 : NTOT);
    const float* invy = inv + (ot == 0 ? NTOT : 2 * NTOT);
    int rowA0 = b * NP + ti * 128;
    int rowB0 = b * NP + tj * 128;

    int tid = threadIdx.x;
    int ty  = tid >> 4, tx = tid & 15;

    float acc[8][8];
    #pragma unroll
    for (int i = 0; i < 8; ++i)
        #pragma unroll
        for (int j = 0; j < 8; ++j) acc[i][j] = 0.0f;

    for (int kb = 0; kb < DF; kb += TK) {
        __syncthreads();
        #pragma unroll
        for (int s = 0; s < 2; ++s) {
            int j4  = tid + s * 256;         // 0..511 over 128x16 tile
            int row = j4 >> 2;
            int c4  = (j4 & 3) * 4;
            float4 av = *reinterpret_cast<const float4*>(X + (size_t)(rowA0 + row) * DF + kb + c4);
            float  sa = invx[rowA0 + row];
            av.x *= sa; av.y *= sa; av.z *= sa; av.w *= sa;
            *reinterpret_cast<float4*>(&As[row][c4]) = av;
            float4 bv = *reinterpret_cast<const float4*>(Y + (size_t)(rowB0 + row) * DF + kb + c4);
            float  sb = invy[rowB0 + row];
            bv.x *= sb; bv.y *= sb; bv.z *= sb; bv.w *= sb;
            *reinterpret_cast<float4*>(&Bs[row][c4]) = bv;
        }
        __syncthreads();
        #pragma unroll
        for (int kk4 = 0; kk4 < TK; kk4 += 4) {
            float4 a[8], bb[8];
            #pragma unroll
            for (int i = 0; i < 8; ++i) a[i]  = *reinterpret_cast<const float4*>(&As[ty + 16 * i][kk4]);
            #pragma unroll
            for (int j = 0; j < 8; ++j) bb[j] = *reinterpret_cast<const float4*>(&Bs[tx + 16 * j][kk4]);
            #pragma unroll
            for (int i = 0; i < 8; ++i)
                #pragma unroll
                for (int j = 0; j < 8; ++j)
                    acc[i][j] += a[i].x * bb[j].x + a[i].y * bb[j].y
                               + a[i].z * bb[j].z + a[i].w * bb[j].w;
        }
    }

    unsigned short* Kp = K + (size_t)p * NP * NP;
    #pragma unroll
    for (int i = 0; i < 8; ++i) {
        int gi = ti * 128 + ty + 16 * i;
        #pragma unroll
        for (int j = 0; j < 8; ++j) {
            int gj = tj * 128 + tx + 16 * j;
            float k = expf(acc[i][j] - 1.0f);
            Kp[(size_t)gi * NP + gj] = (unsigned short)__float2uint_rn(k * SQ);
        }
    }
}

// ---------------------------------------------------------------- one Sinkhorn iteration
// 1024 blocks (8 problems * 128), 16 rows each (4 rows/wave). Reads each u16 K
// row ONCE (packed in regs, unpacked twice): u-dot, then K^T u column partials.
// Cross-wave combine in LDS (write-contiguous swizzled layout), then atomics.
__global__ __launch_bounds__(256, 4) void k_sink(const unsigned short* __restrict__ K,
                                                 float* __restrict__ u,
                                                 const float* __restrict__ vR,
                                                 float* __restrict__ vW,
                                                 float* __restrict__ vZ,
                                                 int first) {
    __shared__ float4 lds[4][512];
    int bid = blockIdx.x;        // 1024 = 8 problems * 128 blocks
    int p   = bid >> 7;
    int blk = bid & 127;
    int tid = threadIdx.x;
    int w   = tid >> 6, lane = tid & 63;

    // zero the Z buffer slice (16384 floats / 1024 blocks = 16 each)
    if (tid < 16) vZ[bid * 16 + tid] = 0.0f;

    // v for the 32 columns this lane owns: cols j*512 + lane*8 + {0..7}
    float vr[32];
    if (first) {
        #pragma unroll
        for (int c = 0; c < 32; ++c) vr[c] = 1.0f;
    } else {
        const float4* vRp = reinterpret_cast<const float4*>(vR + (size_t)p * NP);
        #pragma unroll
        for (int j = 0; j < 4; ++j)
            #pragma unroll
            for (int h = 0; h < 2; ++h) {
                float4 r = vRp[j * 128 + lane * 2 + h];
                vr[j * 8 + h * 4 + 0] = F_MU / (r.x + EPS_V);
                vr[j * 8 + h * 4 + 1] = F_MU / (r.y + EPS_V);
                vr[j * 8 + h * 4 + 2] = F_MU / (r.z + EPS_V);
                vr[j * 8 + h * 4 + 3] = F_MU / (r.w + EPS_V);
            }
    }

    float va[32];
    #pragma unroll
    for (int c = 0; c < 32; ++c) va[c] = 0.0f;

    const unsigned short* Kp = K + (size_t)p * NP * NP;
    int row0 = blk * 16 + w * 4;
    for (int r = 0; r < 4; ++r) {
        int row = row0 + r;
        const uint4* kr = reinterpret_cast<const uint4*>(Kp + (size_t)row * NP);
        uint4 q[4];
        #pragma unroll
        for (int j = 0; j < 4; ++j) q[j] = kr[j * 64 + lane];
        float d = 0.0f;
        #pragma unroll
        for (int j = 0; j < 4; ++j) {
            float4 f01 = unpack4(q[j].x, q[j].y);
            float4 f23 = unpack4(q[j].z, q[j].w);
            d += f01.x * vr[j*8+0] + f01.y * vr[j*8+1] + f01.z * vr[j*8+2] + f01.w * vr[j*8+3]
               + f23.x * vr[j*8+4] + f23.y * vr[j*8+5] + f23.z * vr[j*8+6] + f23.w * vr[j*8+7];
        }
        #pragma unroll
        for (int off = 32; off; off >>= 1) d += __shfl_xor(d, off);
        float ui = F_MU / (d + EPS_U);
        if (lane == 0) u[(size_t)p * NP + row] = ui;
        #pragma unroll
        for (int j = 0; j < 4; ++j) {
            float4 f01 = unpack4(q[j].x, q[j].y);
            float4 f23 = unpack4(q[j].z, q[j].w);
            va[j*8+0] += f01.x * ui; va[j*8+1] += f01.y * ui;
            va[j*8+2] += f01.z * ui; va[j*8+3] += f01.w * ui;
            va[j*8+4] += f23.x * ui; va[j*8+5] += f23.y * ui;
            va[j*8+6] += f23.z * ui; va[j*8+7] += f23.w * ui;
        }
    }

    // cross-wave combine; physical LDS index (j*2+h)*64+lane is write-contiguous
    #pragma unroll
    for (int j = 0; j < 4; ++j)
        #pragma unroll
        for (int h = 0; h < 2; ++h)
            lds[w][(j * 2 + h) * 64 + lane] =
                make_float4(va[j*8+h*4+0], va[j*8+h*4+1], va[j*8+h*4+2], va[j*8+h*4+3]);
    __syncthreads();
    float* vWp = vW + (size_t)p * NP;
    #pragma unroll
    for (int s = 0; s < 2; ++s) {
        int pi = tid + s * 256;               // physical float4 index 0..511
        int lr = pi & 63, hr = (pi >> 6) & 1, jr = pi >> 7;
        int col4 = jr * 128 + lr * 2 + hr;    // logical col/4
        float4 a0 = lds[0][pi], a1 = lds[1][pi], a2 = lds[2][pi], a3 = lds[3][pi];
        atomicAdd(&vWp[4 * col4 + 0], a0.x + a1.x + a2.x + a3.x);
        atomicAdd(&vWp[4 * col4 + 1], a0.y + a1.y + a2.y + a3.y);
        atomicAdd(&vWp[4 * col4 + 2], a0.z + a1.z + a2.z + a3.z);
        atomicAdd(&vWp[4 * col4 + 3], a0.w + a1.w + a2.w + a3.w);
    }
}

// ---------------------------------------------------------------- mean |f1-f2|
__global__ __launch_bounds__(256) void k_freduce(const unsigned short* __restrict__ K,
                                                 const float* __restrict__ u,
                                                 const float* __restrict__ vF,
                                                 float* __restrict__ sum) {
    int bid = blockIdx.x;        // 512 = 4 batches * 128 blocks
    int b   = bid >> 7;
    int blk = bid & 127;
    int tid = threadIdx.x;
    int w   = tid >> 6, lane = tid & 63;
    int p1 = b, p2 = 4 + b;

    float v1[32], v2[32];
    const float4* vF1 = reinterpret_cast<const float4*>(vF + (size_t)p1 * NP);
    const float4* vF2 = reinterpret_cast<const float4*>(vF + (size_t)p2 * NP);
    #pragma unroll
    for (int j = 0; j < 4; ++j)
        #pragma unroll
        for (int h = 0; h < 2; ++h) {
            float4 r1 = vF1[j * 128 + lane * 2 + h];
            float4 r2 = vF2[j * 128 + lane * 2 + h];
            v1[j*8+h*4+0] = F_MU / (r1.x + EPS_V); v1[j*8+h*4+1] = F_MU / (r1.y + EPS_V);
            v1[j*8+h*4+2] = F_MU / (r1.z + EPS_V); v1[j*8+h*4+3] = F_MU / (r1.w + EPS_V);
            v2[j*8+h*4+0] = F_MU / (r2.x + EPS_V); v2[j*8+h*4+1] = F_MU / (r2.y + EPS_V);
            v2[j*8+h*4+2] = F_MU / (r2.z + EPS_V); v2[j*8+h*4+3] = F_MU / (r2.w + EPS_V);
        }
    const unsigned short* K1 = K + (size_t)p1 * NP * NP;
    const unsigned short* K2 = K + (size_t)p2 * NP * NP;
    float acc = 0.0f;
    int row0 = blk * 16 + w * 4;
    for (int r = 0; r < 4; ++r) {
        int row = row0 + r;
        float u1 = u[(size_t)p1 * NP + row], u2 = u[(size_t)p2 * NP + row];
        const uint4* kr1 = reinterpret_cast<const uint4*>(K1 + (size_t)row * NP);
        const uint4* kr2 = reinterpret_cast<const uint4*>(K2 + (size_t)row * NP);
        #pragma unroll
        for (int j = 0; j < 4; ++j) {
            uint4 q1 = kr1[j * 64 + lane];
            uint4 q2 = kr2[j * 64 + lane];
            float4 a01 = unpack4(q1.x, q1.y), a23 = unpack4(q1.z, q1.w);
            float4 b01 = unpack4(q2.x, q2.y), b23 = unpack4(q2.z, q2.w);
            acc += fabsf(u1 * a01.x * v1[j*8+0] - u2 * b01.x * v2[j*8+0]);
            acc += fabsf(u1 * a01.y * v1[j*8+1] - u2 * b01.y * v2[j*8+1]);
            acc += fabsf(u1 * a01.z * v1[j*8+2] - u2 * b01.z * v2[j*8+2]);
            acc += fabsf(u1 * a01.w * v1[j*8+3] - u2 * b01.w * v2[j*8+3]);
            acc += fabsf(u1 * a23.x * v1[j*8+4] - u2 * b23.x * v2[j*8+4]);
            acc += fabsf(u1 * a23.y * v1[j*8+5] - u2 * b23.y * v2[j*8+5]);
            acc += fabsf(u1 * a23.z * v1[j*8+6] - u2 * b23.z * v2[j*8+6]);
            acc += fabsf(u1 * a23.w * v1[j*8+7] - u2 * b23.w * v2[j*8+7]);
        }
    }
    #pragma unroll
    for (int off = 32; off; off >>= 1) acc += __shfl_xor(acc, off);
    __shared__ float red[4];
    if (lane == 0) red[w] = acc;
    __syncthreads();
    if (tid == 0) atomicAdd(sum, red[0] + red[1] + red[2] + red[3]);
}

__global__ void k_final(const float* __restrict__ sum, float* __restrict__ out) {
    out[0] = sum[0] * (1.0f / 16777216.0f);   // / (4*2048*2048)
}

// ---------------------------------------------------------------- launch
extern "C" void kernel_launch(void* const* d_in, const int* in_sizes, int n_in,
                              void* d_out, int out_size, void* d_ws, size_t ws_size,
                              hipStream_t stream) {
    const float* src = (const float*)d_in[0];
    const float* tgt = (const float*)d_in[1];
    const float* gen = (const float*)d_in[2];
    float* ws  = (float*)d_ws;
    unsigned short* Kq = (unsigned short*)(ws + OFF_K);
    float* va  = ws + OFF_VA;
    float* uu  = ws + OFF_U;
    float* inv = ws + OFF_INV;
    float* sum = ws + OFF_SUM;
    float* out = (float*)d_out;

    hipLaunchKernelGGL(k_norms, dim3(6144), dim3(256), 0, stream, src, tgt, gen, inv);
    hipLaunchKernelGGL(k_init,  dim3(65),   dim3(256), 0, stream, va, sum);
    hipLaunchKernelGGL(k_build, dim3(2048), dim3(256), 0, stream, src, tgt, gen, inv, Kq);
    for (int t = 0; t < 50; ++t) {
        float* R = va + ((size_t)((t + 2) % 3)) * (NPROB * NP);  // read (iter t-1 result)
        float* W = va + ((size_t)(t % 3))       * (NPROB * NP);  // accumulate
        float* Z = va + ((size_t)((t + 1) % 3)) * (NPROB * NP);  // zero for iter t+1
        hipLaunchKernelGGL(k_sink, dim3(1024), dim3(256), 0, stream,
                           Kq, uu, R, W, Z, (t == 0) ? 1 : 0);
    }
    // final v is in buffer (49 % 3) == 1
    hipLaunchKernelGGL(k_freduce, dim3(512), dim3(256), 0, stream,
                       Kq, uu, va + (size_t)1 * (NPROB * NP), sum);
    hipLaunchKernelGGL(k_final, dim3(1), dim3(1), 0, stream, sum, out);
}

// Round 3
// 2620.058 us; speedup vs baseline: 2.0573x; 2.0573x over previous
//
#include <hip/hip_runtime.h>
#include <math.h>

#define NP 2048           // points per batch (n == m)
#define DF 256            // feature dim
#define NPROB 8           // 2 OTs * 4 batches
#define NTOT 8192         // total rows per feature tensor

constexpr float F_MU  = 1.0f / 2048.0f;   // uniform marginal 1/n
constexpr float SQ    = 65535.0f;         // K u16 quantization scale
constexpr float EPS_U = 65535.0f * 1e-8f; // stab for u-update (scale-consistent)
constexpr float EPS_V = 1e-8f;            // stab for v-update (unscaled)

typedef _Float16 f16x8 __attribute__((ext_vector_type(8)));
typedef float    f32x4 __attribute__((ext_vector_type(4)));

// workspace layout (float units)
constexpr size_t OFF_K   = 0;                            // ushort[8*2048*2048]
constexpr size_t SZ_Kf   = (size_t)NPROB * NP * NP / 2;  // 16,777,216 floats
constexpr size_t OFF_VA  = OFF_K + SZ_Kf;                // 3 ping-pong-pong buffers
constexpr size_t SZ_VA   = (size_t)3 * NPROB * NP;
constexpr size_t OFF_U   = OFF_VA + SZ_VA;
constexpr size_t SZ_U    = (size_t)NPROB * NP;
constexpr size_t OFF_INV = OFF_U + SZ_U;
constexpr size_t SZ_INV  = (size_t)3 * NTOT;
constexpr size_t OFF_SUM = OFF_INV + SZ_INV;

__device__ inline float4 unpack4(unsigned a, unsigned b) {
    return make_float4((float)(a & 0xffffu), (float)(a >> 16),
                       (float)(b & 0xffffu), (float)(b >> 16));
}

// ---------------------------------------------------------------- row norms
__global__ __launch_bounds__(256) void k_norms(const float* __restrict__ src,
                                               const float* __restrict__ tgt,
                                               const float* __restrict__ gen,
                                               float* __restrict__ inv) {
    int gw   = (blockIdx.x * 256 + threadIdx.x) >> 6;   // 0 .. 3*8192-1
    int lane = threadIdx.x & 63;
    int a = gw >> 13;
    int r = gw & 8191;
    const float* base = (a == 0 ? src : (a == 1 ? tgt : gen)) + (size_t)r * DF;
    float4 x = reinterpret_cast<const float4*>(base)[lane];
    float s = x.x * x.x + x.y * x.y + x.z * x.z + x.w * x.w;
    #pragma unroll
    for (int off = 32; off; off >>= 1) s += __shfl_xor(s, off);
    if (lane == 0) inv[gw] = 1.0f / (sqrtf(s) + 1e-8f);
}

// ---------------------------------------------------------------- zero init
__global__ void k_init(float* __restrict__ va0, float* __restrict__ sum) {
    int i = blockIdx.x * 256 + threadIdx.x;
    if (i < NPROB * NP) va0[i] = 0.0f;
    if (i == 0) sum[0] = 0.0f;
}

// ---------------------------------------------------------------- K build via f16 MFMA
// 128x128 tile per block, 4 waves in 2x2, each wave 64x64 via 4x4 fragments of
// mfma_f32_16x16x32_f16. BK=128 K-panel staged in LDS (f16, XOR granule
// swizzle g^=(row&7) -> 2-way-free b128 reads). Epilogue: exp + u16 quantize.
#define BK 128
__global__ __launch_bounds__(256) void k_build(const float* __restrict__ src,
                                               const float* __restrict__ tgt,
                                               const float* __restrict__ gen,
                                               const float* __restrict__ inv,
                                               unsigned short* __restrict__ K) {
    __shared__ _Float16 As[128 * BK];   // 32 KB, row stride 128 halfs = 16 granules
    __shared__ _Float16 Bs[128 * BK];   // 32 KB
    int bid = blockIdx.x;          // 2048 = 8 problems * 16 * 16 tiles
    int p   = bid >> 8;
    int t   = bid & 255;
    int ti  = t >> 4, tj = t & 15;
    int ot  = p >> 2, b = p & 3;
    const float* X    = (ot == 0) ? src : tgt;
    const float* Y    = (ot == 0) ? tgt : gen;
    const float* invx = inv + (ot == 0 ? 0 : NTOT);
    const float* invy = inv + (ot == 0 ? NTOT : 2 * NTOT);
    int rowA0 = b * NP + ti * 128;
    int rowB0 = b * NP + tj * 128;

    int tid  = threadIdx.x;
    int w    = tid >> 6, lane = tid & 63;
    int wr   = w >> 1,  wc   = w & 1;
    int lr   = lane & 15, lk = lane >> 4;   // fragment row / k-group

    f32x4 acc[4][4];
    #pragma unroll
    for (int m = 0; m < 4; ++m)
        #pragma unroll
        for (int n = 0; n < 4; ++n) acc[m][n] = (f32x4){0.f, 0.f, 0.f, 0.f};

    for (int kb = 0; kb < DF; kb += BK) {
        __syncthreads();
        // stage 128 rows x 128 cols f16 for both matrices; 2048 granules each
        #pragma unroll
        for (int s = 0; s < 8; ++s) {
            int idx = tid + s * 256;      // 0..2047
            int row = idx >> 4;           // 16 granules (16B) per row
            int g   = idx & 15;
            int gs  = g ^ (row & 7);      // XOR swizzle
            const float4* xp = reinterpret_cast<const float4*>(
                X + (size_t)(rowA0 + row) * DF + kb + g * 8);
            float4 x0 = xp[0], x1 = xp[1];
            float  sa = invx[rowA0 + row];
            f16x8 hv;
            hv[0] = (_Float16)(x0.x * sa); hv[1] = (_Float16)(x0.y * sa);
            hv[2] = (_Float16)(x0.z * sa); hv[3] = (_Float16)(x0.w * sa);
            hv[4] = (_Float16)(x1.x * sa); hv[5] = (_Float16)(x1.y * sa);
            hv[6] = (_Float16)(x1.z * sa); hv[7] = (_Float16)(x1.w * sa);
            *reinterpret_cast<f16x8*>(&As[row * BK + gs * 8]) = hv;
            const float4* yp = reinterpret_cast<const float4*>(
                Y + (size_t)(rowB0 + row) * DF + kb + g * 8);
            float4 y0 = yp[0], y1 = yp[1];
            float  sb = invy[rowB0 + row];
            f16x8 hw;
            hw[0] = (_Float16)(y0.x * sb); hw[1] = (_Float16)(y0.y * sb);
            hw[2] = (_Float16)(y0.z * sb); hw[3] = (_Float16)(y0.w * sb);
            hw[4] = (_Float16)(y1.x * sb); hw[5] = (_Float16)(y1.y * sb);
            hw[6] = (_Float16)(y1.z * sb); hw[7] = (_Float16)(y1.w * sb);
            *reinterpret_cast<f16x8*>(&Bs[row * BK + gs * 8]) = hw;
        }
        __syncthreads();
        #pragma unroll
        for (int ks = 0; ks < BK / 32; ++ks) {
            int kg = ks * 4 + lk;         // granule within row for this lane
            f16x8 af[4], bf[4];
            #pragma unroll
            for (int m = 0; m < 4; ++m) {
                int row = wr * 64 + m * 16 + lr;
                af[m] = *reinterpret_cast<const f16x8*>(&As[row * BK + (kg ^ (row & 7)) * 8]);
            }
            #pragma unroll
            for (int n = 0; n < 4; ++n) {
                int row = wc * 64 + n * 16 + lr;
                bf[n] = *reinterpret_cast<const f16x8*>(&Bs[row * BK + (kg ^ (row & 7)) * 8]);
            }
            #pragma unroll
            for (int m = 0; m < 4; ++m)
                #pragma unroll
                for (int n = 0; n < 4; ++n)
                    acc[m][n] = __builtin_amdgcn_mfma_f32_16x16x32_f16(af[m], bf[n], acc[m][n], 0, 0, 0);
        }
    }

    // epilogue: C/D layout col = lane&15, row = (lane>>4)*4 + reg
    unsigned short* Kp = K + (size_t)p * NP * NP;
    #pragma unroll
    for (int m = 0; m < 4; ++m) {
        #pragma unroll
        for (int r4 = 0; r4 < 4; ++r4) {
            int gi = ti * 128 + wr * 64 + m * 16 + lk * 4 + r4;
            #pragma unroll
            for (int n = 0; n < 4; ++n) {
                int gj = tj * 128 + wc * 64 + n * 16 + lr;
                float kv = __expf(acc[m][n][r4] - 1.0f);
                Kp[(size_t)gi * NP + gj] =
                    (unsigned short)__float2uint_rn(fminf(kv * SQ, 65535.0f));
            }
        }
    }
}

// ---------------------------------------------------------------- one Sinkhorn iteration
// Round-1 structure (measured 33 us in f32): 512 blocks, 32 rows/block,
// 8 rows/wave. u16 K: packed uint4 row kept in regs, unpacked twice
// (u-dot, then K^T u partials). NO min-waves clamp (spill risk).
__global__ __launch_bounds__(256) void k_sink(const unsigned short* __restrict__ K,
                                              float* __restrict__ u,
                                              const float* __restrict__ vR,
                                              float* __restrict__ vW,
                                              float* __restrict__ vZ,
                                              int first) {
    __shared__ float4 lds[4][512];
    int bid = blockIdx.x;        // 512 = 8 problems * 64 blocks
    int p   = bid >> 6;
    int blk = bid & 63;
    int tid = threadIdx.x;
    int w   = tid >> 6, lane = tid & 63;

    // zero the Z buffer slice (16384 floats / 512 blocks = 32 each)
    if (tid < 32) vZ[bid * 32 + tid] = 0.0f;

    // v for the 32 columns this lane owns: cols (j*64+lane)*8 + {0..7}
    float vr[32];
    if (first) {
        #pragma unroll
        for (int c = 0; c < 32; ++c) vr[c] = 1.0f;
    } else {
        const float4* vRp = reinterpret_cast<const float4*>(vR + (size_t)p * NP);
        #pragma unroll
        for (int j = 0; j < 4; ++j)
            #pragma unroll
            for (int h = 0; h < 2; ++h) {
                float4 r = vRp[j * 128 + lane * 2 + h];
                vr[j * 8 + h * 4 + 0] = F_MU / (r.x + EPS_V);
                vr[j * 8 + h * 4 + 1] = F_MU / (r.y + EPS_V);
                vr[j * 8 + h * 4 + 2] = F_MU / (r.z + EPS_V);
                vr[j * 8 + h * 4 + 3] = F_MU / (r.w + EPS_V);
            }
    }

    float va[32];
    #pragma unroll
    for (int c = 0; c < 32; ++c) va[c] = 0.0f;

    const unsigned short* Kp = K + (size_t)p * NP * NP;
    int row0 = blk * 32 + w * 8;
    for (int r = 0; r < 8; ++r) {
        int row = row0 + r;
        const uint4* kr = reinterpret_cast<const uint4*>(Kp + (size_t)row * NP);
        uint4 q[4];
        #pragma unroll
        for (int j = 0; j < 4; ++j) q[j] = kr[j * 64 + lane];
        float d = 0.0f;
        #pragma unroll
        for (int j = 0; j < 4; ++j) {
            float4 f01 = unpack4(q[j].x, q[j].y);
            float4 f23 = unpack4(q[j].z, q[j].w);
            d += f01.x * vr[j*8+0] + f01.y * vr[j*8+1] + f01.z * vr[j*8+2] + f01.w * vr[j*8+3]
               + f23.x * vr[j*8+4] + f23.y * vr[j*8+5] + f23.z * vr[j*8+6] + f23.w * vr[j*8+7];
        }
        #pragma unroll
        for (int off = 32; off; off >>= 1) d += __shfl_xor(d, off);
        float ui = F_MU / (d + EPS_U);
        if (lane == 0) u[(size_t)p * NP + row] = ui;
        #pragma unroll
        for (int j = 0; j < 4; ++j) {
            float4 f01 = unpack4(q[j].x, q[j].y);
            float4 f23 = unpack4(q[j].z, q[j].w);
            va[j*8+0] += f01.x * ui; va[j*8+1] += f01.y * ui;
            va[j*8+2] += f01.z * ui; va[j*8+3] += f01.w * ui;
            va[j*8+4] += f23.x * ui; va[j*8+5] += f23.y * ui;
            va[j*8+6] += f23.z * ui; va[j*8+7] += f23.w * ui;
        }
    }

    // cross-wave combine; physical LDS index (j*2+h)*64+lane is write-contiguous
    #pragma unroll
    for (int j = 0; j < 4; ++j)
        #pragma unroll
        for (int h = 0; h < 2; ++h)
            lds[w][(j * 2 + h) * 64 + lane] =
                make_float4(va[j*8+h*4+0], va[j*8+h*4+1], va[j*8+h*4+2], va[j*8+h*4+3]);
    __syncthreads();
    float* vWp = vW + (size_t)p * NP;
    #pragma unroll
    for (int s = 0; s < 2; ++s) {
        int pi = tid + s * 256;               // physical float4 index 0..511
        int lr = pi & 63, hr = (pi >> 6) & 1, jr = pi >> 7;
        int col4 = jr * 128 + lr * 2 + hr;    // logical col/4
        float4 a0 = lds[0][pi], a1 = lds[1][pi], a2 = lds[2][pi], a3 = lds[3][pi];
        atomicAdd(&vWp[4 * col4 + 0], a0.x + a1.x + a2.x + a3.x);
        atomicAdd(&vWp[4 * col4 + 1], a0.y + a1.y + a2.y + a3.y);
        atomicAdd(&vWp[4 * col4 + 2], a0.z + a1.z + a2.z + a3.z);
        atomicAdd(&vWp[4 * col4 + 3], a0.w + a1.w + a2.w + a3.w);
    }
}

// ---------------------------------------------------------------- mean |f1-f2|
// v1/v2 staged in LDS (not 64 regs/lane) to keep VGPRs low.
__global__ __launch_bounds__(256) void k_freduce(const unsigned short* __restrict__ K,
                                                 const float* __restrict__ u,
                                                 const float* __restrict__ vF,
                                                 float* __restrict__ sum) {
    __shared__ float vsh[2][NP];   // 16 KB
    int bid = blockIdx.x;        // 512 = 4 batches * 128 blocks
    int b   = bid >> 7;
    int blk = bid & 127;
    int tid = threadIdx.x;
    int w   = tid >> 6, lane = tid & 63;
    int p1 = b, p2 = 4 + b;

    #pragma unroll
    for (int s = 0; s < 8; ++s) {
        int i = tid + s * 256;
        vsh[0][i] = F_MU / (vF[(size_t)p1 * NP + i] + EPS_V);
        vsh[1][i] = F_MU / (vF[(size_t)p2 * NP + i] + EPS_V);
    }
    __syncthreads();

    const unsigned short* K1 = K + (size_t)p1 * NP * NP;
    const unsigned short* K2 = K + (size_t)p2 * NP * NP;
    float acc = 0.0f;
    int row0 = blk * 16 + w * 4;
    for (int r = 0; r < 4; ++r) {
        int row = row0 + r;
        float u1 = u[(size_t)p1 * NP + row], u2 = u[(size_t)p2 * NP + row];
        const uint4* kr1 = reinterpret_cast<const uint4*>(K1 + (size_t)row * NP);
        const uint4* kr2 = reinterpret_cast<const uint4*>(K2 + (size_t)row * NP);
        #pragma unroll
        for (int j = 0; j < 4; ++j) {
            uint4 q1 = kr1[j * 64 + lane];
            uint4 q2 = kr2[j * 64 + lane];
            int cb = (j * 64 + lane) * 8;
            float4 v1a = *reinterpret_cast<const float4*>(&vsh[0][cb]);
            float4 v1b = *reinterpret_cast<const float4*>(&vsh[0][cb + 4]);
            float4 v2a = *reinterpret_cast<const float4*>(&vsh[1][cb]);
            float4 v2b = *reinterpret_cast<const float4*>(&vsh[1][cb + 4]);
            float4 a01 = unpack4(q1.x, q1.y), a23 = unpack4(q1.z, q1.w);
            float4 b01 = unpack4(q2.x, q2.y), b23 = unpack4(q2.z, q2.w);
            acc += fabsf(u1 * a01.x * v1a.x - u2 * b01.x * v2a.x);
            acc += fabsf(u1 * a01.y * v1a.y - u2 * b01.y * v2a.y);
            acc += fabsf(u1 * a01.z * v1a.z - u2 * b01.z * v2a.z);
            acc += fabsf(u1 * a01.w * v1a.w - u2 * b01.w * v2a.w);
            acc += fabsf(u1 * a23.x * v1b.x - u2 * b23.x * v2b.x);
            acc += fabsf(u1 * a23.y * v1b.y - u2 * b23.y * v2b.y);
            acc += fabsf(u1 * a23.z * v1b.z - u2 * b23.z * v2b.z);
            acc += fabsf(u1 * a23.w * v1b.w - u2 * b23.w * v2b.w);
        }
    }
    #pragma unroll
    for (int off = 32; off; off >>= 1) acc += __shfl_xor(acc, off);
    __shared__ float red[4];
    if (lane == 0) red[w] = acc;
    __syncthreads();
    if (tid == 0) atomicAdd(sum, red[0] + red[1] + red[2] + red[3]);
}

__global__ void k_final(const float* __restrict__ sum, float* __restrict__ out) {
    out[0] = sum[0] * (1.0f / 16777216.0f);   // / (4*2048*2048)
}

// ---------------------------------------------------------------- launch
extern "C" void kernel_launch(void* const* d_in, const int* in_sizes, int n_in,
                              void* d_out, int out_size, void* d_ws, size_t ws_size,
                              hipStream_t stream) {
    const float* src = (const float*)d_in[0];
    const float* tgt = (const float*)d_in[1];
    const float* gen = (const float*)d_in[2];
    float* ws  = (float*)d_ws;
    unsigned short* Kq = (unsigned short*)(ws + OFF_K);
    float* va  = ws + OFF_VA;
    float* uu  = ws + OFF_U;
    float* inv = ws + OFF_INV;
    float* sum = ws + OFF_SUM;
    float* out = (float*)d_out;

    hipLaunchKernelGGL(k_norms, dim3(6144), dim3(256), 0, stream, src, tgt, gen, inv);
    hipLaunchKernelGGL(k_init,  dim3(65),   dim3(256), 0, stream, va, sum);
    hipLaunchKernelGGL(k_build, dim3(2048), dim3(256), 0, stream, src, tgt, gen, inv, Kq);
    for (int t = 0; t < 50; ++t) {
        float* R = va + ((size_t)((t + 2) % 3)) * (NPROB * NP);  // read (iter t-1 result)
        float* W = va + ((size_t)(t % 3))       * (NPROB * NP);  // accumulate
        float* Z = va + ((size_t)((t + 1) % 3)) * (NPROB * NP);  // zero for iter t+1
        hipLaunchKernelGGL(k_sink, dim3(512), dim3(256), 0, stream,
                           Kq, uu, R, W, Z, (t == 0) ? 1 : 0);
    }
    // final v is in buffer (49 % 3) == 1
    hipLaunchKernelGGL(k_freduce, dim3(512), dim3(256), 0, stream,
                       Kq, uu, va + (size_t)1 * (NPROB * NP), sum);
    hipLaunchKernelGGL(k_final, dim3(1), dim3(1), 0, stream, sum, out);
}